// Round 6
// baseline (524.832 us; speedup 1.0000x reference)
//
#include <hip/hip_runtime.h>
#include <hip/hip_bf16.h>

#define DEV __device__ __forceinline__

typedef short bf16x8 __attribute__((ext_vector_type(8)));
typedef short bf16x4 __attribute__((ext_vector_type(4)));
typedef float f32x4 __attribute__((ext_vector_type(4)));

static constexpr int B_  = 4;
static constexpr int S_  = 1024;
static constexpr int H_  = 1024;
static constexpr int NH_ = 16;
static constexpr int DH_ = 64;
static constexpr int BS_ = B_ * S_;   // 4096
static constexpr int H6_ = 6 * H_;    // 6144

// ---------------- async global->LDS (16B per lane) ----------------
DEV void gld16(const void* g, void* l) {
  __builtin_amdgcn_global_load_lds(
      (__attribute__((address_space(1))) void*)(unsigned long long)g,
      (__attribute__((address_space(3))) void*)(unsigned)(unsigned long long)l,
      16, 0, 0);
}

// 16x16x16 bf16 MFMA (A-frag layout matches C-layout of transposed scores)
DEV f32x4 pv_mfma(bf16x4 a, bf16x4 b, f32x4 c) {
#if __has_builtin(__builtin_amdgcn_mfma_f32_16x16x16bf16_1k)
  return __builtin_amdgcn_mfma_f32_16x16x16bf16_1k(a, b, c, 0, 0, 0);
#else
  asm volatile("v_mfma_f32_16x16x16_bf16 %0, %1, %2, %0" : "+v"(c) : "v"(a), "v"(b));
  return c;
#endif
}

// ---------------- reductions (blockDim == 256) ----------------
DEV float wred_sum(float v) {
#pragma unroll
  for (int o = 32; o; o >>= 1) v += __shfl_xor(v, o);
  return v;
}
DEV float bred_sum(float v, float* sh) {
  v = wred_sum(v);
  const int tid = threadIdx.x;
  if ((tid & 63) == 0) sh[tid >> 6] = v;
  __syncthreads();
  v = sh[0] + sh[1] + sh[2] + sh[3];
  __syncthreads();
  return v;
}
DEV float geluf(float x) { return 0.5f * x * (1.f + erff(x * 0.70710678118654752f)); }

// ---------------- prep: casts + weff + rowsum in ONE dispatch ----------------
struct CastSeg { const float* src; unsigned short* dst; int n; };
struct PrepArgs {
  CastSeg s[7];
  const float* wt; const float* wout; float* weff;
  const float* w1; float* rsum;
};
__global__ __launch_bounds__(256) void prep_k(PrepArgs a) {
  const int y = blockIdx.y, tid = threadIdx.x;
  if (y < 7) {
    const CastSeg g = a.s[y];
    int i = (blockIdx.x * 256 + tid) * 4;
    if (i >= g.n) return;
    float4 v = *(const float4*)(g.src + i);
    __hip_bfloat16 o0 = __float2bfloat16(v.x), o1 = __float2bfloat16(v.y);
    __hip_bfloat16 o2 = __float2bfloat16(v.z), o3 = __float2bfloat16(v.w);
    ushort4 o;
    o.x = *(unsigned short*)&o0; o.y = *(unsigned short*)&o1;
    o.z = *(unsigned short*)&o2; o.w = *(unsigned short*)&o3;
    *(ushort4*)(g.dst + i) = o;
  } else if (y == 7) {
    // weff[n,h] = sum_o wt[n,o]*wout[o,h]; 16 blocks, exclusive outputs
    if (blockIdx.x >= 16) return;
    const int h = blockIdx.x * 64 + (tid & 63), ng = tid >> 6;
    float acc[4] = {0.f, 0.f, 0.f, 0.f};
    for (int o = 0; o < H_; o++) {
      float wv = a.wout[(size_t)o * H_ + h];
#pragma unroll
      for (int i = 0; i < 4; i++) acc[i] += a.wt[(size_t)(ng * 4 + i) * H_ + o] * wv;
    }
#pragma unroll
    for (int i = 0; i < 4; i++) a.weff[(size_t)(ng * 4 + i) * H_ + h] = acc[i];
  } else {
    // rowsum of W1b (fp32 exact)
    if (blockIdx.x >= 256) return;
    const int row = blockIdx.x * 4 + (tid >> 6), lane = tid & 63;
    float s = 0.f;
#pragma unroll
    for (int j = 0; j < 16; j++) s += a.w1[(size_t)row * 2048 + 1024 + lane + j * 64];
    s = wred_sum(s);
    if (lane == 0) a.rsum[row] = s;
  }
}

// ---------------- QKV GEMM (N=6144) with V-transposed epilogue ----------------
// C[M,6144] = x[M,1024] * wcat[6144,1024]^T. Q/K blocks -> qkv2 rows (bf16);
// V blocks (bx in [16,24)u[40,48)) -> vt2[bh2][d][s] via LDS repack.
__global__ __launch_bounds__(256) void gemm_qkv_k(
    const __hip_bfloat16* __restrict__ Ap, const __hip_bfloat16* __restrict__ Wp,
    __hip_bfloat16* __restrict__ Cp, __hip_bfloat16* __restrict__ vt2) {
  constexpr int BK = 32;
  __shared__ __align__(16) short smem[8448];  // sA(4096)+sB(4096) aliased w/ sT(8448)
  short* sA = smem;
  short* sB = smem + 4096;
  short* sT = smem;
  const int tid = threadIdx.x;
  const int wave = tid >> 6, lane = tid & 63;
  const int wm = wave >> 1, wn = wave & 1;
  const int lr = lane & 15, kq = lane >> 4;
  const int bx = blockIdx.x, by = blockIdx.y;
  const short* Ab = (const short*)Ap + (long long)by * 128 * H_;
  const short* Wb = (const short*)Wp + (long long)bx * 128 * H_;

  f32x4 acc[4][4];
#pragma unroll
  for (int i = 0; i < 4; i++)
#pragma unroll
    for (int j = 0; j < 4; j++) acc[i][j] = f32x4{0.f, 0.f, 0.f, 0.f};

  for (int k0 = 0; k0 < H_; k0 += BK) {
#pragma unroll
    for (int r = 0; r < 2; r++) {
      int idx = r * 256 + tid;
      gld16(Ab + (long long)(idx >> 2) * H_ + k0 + (idx & 3) * 8, sA + (size_t)idx * 8);
    }
#pragma unroll
    for (int r = 0; r < 2; r++) {
      int idx = r * 256 + tid;
      gld16(Wb + (long long)(idx >> 2) * H_ + k0 + (idx & 3) * 8, sB + (size_t)idx * 8);
    }
    __syncthreads();
    bf16x8 af[4], bfr[4];
#pragma unroll
    for (int i = 0; i < 4; i++)
      af[i] = *(const bf16x8*)(sA + (wm * 64 + i * 16 + lr) * BK + kq * 8);
#pragma unroll
    for (int j = 0; j < 4; j++)
      bfr[j] = *(const bf16x8*)(sB + (wn * 64 + j * 16 + lr) * BK + kq * 8);
#pragma unroll
    for (int i = 0; i < 4; i++)
#pragma unroll
      for (int j = 0; j < 4; j++)
        acc[i][j] = __builtin_amdgcn_mfma_f32_16x16x32_bf16(af[i], bfr[j], acc[i][j], 0, 0, 0);
    __syncthreads();
  }

  const bool isV = (bx >= 16 && bx < 24) || (bx >= 40);
  if (!isV) {
    const long long row0 = (long long)by * 128 + wm * 64 + kq * 4;
    const long long col0 = (long long)bx * 128 + wn * 64 + lr;
#pragma unroll
    for (int i = 0; i < 4; i++)
#pragma unroll
      for (int j = 0; j < 4; j++)
#pragma unroll
        for (int r = 0; r < 4; r++)
          Cp[(row0 + i * 16 + r) * H6_ + col0 + j * 16] = __float2bfloat16(acc[i][j][r]);
  } else {
    const int sel = bx >= 40;
    const int h0 = (bx - (sel ? 40 : 16)) * 2;
    const int b = by >> 3, s0 = (by & 7) * 128;
#pragma unroll
    for (int hh = 0; hh < 2; hh++) {
      __syncthreads();
      if (wn == hh) {
#pragma unroll
        for (int i = 0; i < 4; i++)
#pragma unroll
          for (int j = 0; j < 4; j++)
#pragma unroll
            for (int r = 0; r < 4; r++) {
              __hip_bfloat16 v = __float2bfloat16(acc[i][j][r]);
              sT[(j * 16 + lr) * 132 + wm * 64 + i * 16 + kq * 4 + r] = *(short*)&v;
            }
      }
      __syncthreads();
      const int bh2 = sel * 64 + b * 16 + h0 + hh;
      short* dst = (short*)vt2 + (size_t)bh2 * DH_ * S_ + s0;
#pragma unroll
      for (int c = 0; c < 8; c++) {
        int flat = c * 256 + tid;
        int d = flat >> 5, s4 = (flat & 31) * 4;
        *(short4*)(dst + (size_t)d * S_ + s4) = *(short4*)(sT + d * 132 + s4);
      }
    }
  }
}

// ---------------- generic MFMA GEMM (fp32 out), MID dual-A variant ----------------
template <int MT, int NT, int WR, int WC, bool MID>
__global__ __launch_bounds__(256) void gemm_bt(
    const __hip_bfloat16* __restrict__ Ap, const __hip_bfloat16* __restrict__ Wp,
    float* __restrict__ Cp, int K, int lda, int ldw, int ldc,
    const __hip_bfloat16* __restrict__ Ap2, float* __restrict__ Cmid, int kmid) {
  constexpr int BM = WR * MT * 16;
  constexpr int BN = WC * NT * 16;
  constexpr int BK = 32;
  __shared__ __align__(16) short sA[BM * BK];
  __shared__ __align__(16) short sB[BN * BK];
  const int tid = threadIdx.x;
  const int wave = tid >> 6, lane = tid & 63;
  const int wm = wave / WC, wn = wave % WC;
  const int lr = lane & 15, kq = lane >> 4;
  const short* Ab = (const short*)Ap + (long long)blockIdx.y * BM * lda;
  const short* Ab2 = MID ? (const short*)Ap2 + (long long)blockIdx.y * BM * lda : nullptr;
  const short* Wb = (const short*)Wp + (long long)blockIdx.x * BN * ldw;
  const long long row0 = (long long)blockIdx.y * BM + wm * MT * 16 + kq * 4;
  const long long col0 = (long long)blockIdx.x * BN + wn * NT * 16 + lr;

  f32x4 acc[MT][NT];
#pragma unroll
  for (int i = 0; i < MT; i++)
#pragma unroll
    for (int j = 0; j < NT; j++) acc[i][j] = f32x4{0.f, 0.f, 0.f, 0.f};

  for (int k0 = 0; k0 < K; k0 += BK) {
    const short* Asrc;
    int ka;
    if (MID && k0 >= kmid) { Asrc = Ab2; ka = k0 - kmid; }
    else { Asrc = Ab; ka = k0; }
#pragma unroll
    for (int r = 0; r < BM / 64; r++) {
      int idx = r * 256 + tid;
      gld16(Asrc + (long long)(idx >> 2) * lda + ka + (idx & 3) * 8, sA + (size_t)idx * 8);
    }
#pragma unroll
    for (int r = 0; r < BN / 64; r++) {
      int idx = r * 256 + tid;
      gld16(Wb + (long long)(idx >> 2) * ldw + k0 + (idx & 3) * 8, sB + (size_t)idx * 8);
    }
    __syncthreads();
    bf16x8 af[MT], bfr[NT];
#pragma unroll
    for (int i = 0; i < MT; i++)
      af[i] = *(const bf16x8*)(sA + (wm * MT * 16 + i * 16 + lr) * BK + kq * 8);
#pragma unroll
    for (int j = 0; j < NT; j++)
      bfr[j] = *(const bf16x8*)(sB + (wn * NT * 16 + j * 16 + lr) * BK + kq * 8);
#pragma unroll
    for (int i = 0; i < MT; i++)
#pragma unroll
      for (int j = 0; j < NT; j++)
        acc[i][j] = __builtin_amdgcn_mfma_f32_16x16x32_bf16(af[i], bfr[j], acc[i][j], 0, 0, 0);
    if constexpr (MID) {
      if (k0 + BK == kmid) {
#pragma unroll
        for (int i = 0; i < MT; i++)
#pragma unroll
          for (int j = 0; j < NT; j++)
#pragma unroll
            for (int r = 0; r < 4; r++)
              Cmid[(row0 + i * 16 + r) * ldc + col0 + j * 16] = acc[i][j][r];
      }
    }
    __syncthreads();
  }
#pragma unroll
  for (int i = 0; i < MT; i++)
#pragma unroll
    for (int j = 0; j < NT; j++)
#pragma unroll
      for (int r = 0; r < 4; r++)
        Cp[(row0 + i * 16 + r) * ldc + col0 + j * 16] = acc[i][j][r];
}

// ---------------- fused flash attention (no online max: scores bounded) ----------------
template <bool TTM>
__global__ __launch_bounds__(256) void flash_k(
    const __hip_bfloat16* __restrict__ qkvB,
    const __hip_bfloat16* __restrict__ vt,
    const float* __restrict__ twn,
    __hip_bfloat16* __restrict__ ctx,
    float scale, int ldq) {
  __shared__ __align__(16) short sK[2][128 * 64];
  __shared__ __align__(16) short sVT[2][64 * 128];
  const int bh = blockIdx.x, b = bh >> 4, h = bh & 15;
  const int qb = blockIdx.y;
  const int tid = threadIdx.x, lane = tid & 63, wid = tid >> 6;
  const int lr = lane & 15, quad = lane >> 4;
  const short* qg = (const short*)qkvB + ((size_t)(b * S_) + qb * 128) * ldq + h * 64;
  const short* kg = (const short*)qkvB + (size_t)b * S_ * ldq + H_ + h * 64;
  const short* vg = (const short*)vt + (size_t)bh * DH_ * S_;

  auto stage = [&](int kt, int buf) {
#pragma unroll
    for (int i = 0; i < 4; i++) {
      int idx = i * 256 + tid;
      int row = idx >> 3, cp = idx & 7;
      int c = cp ^ (row & 7);
      gld16(kg + (size_t)(kt * 128 + row) * ldq + c * 8, &sK[buf][(size_t)idx * 8]);
    }
#pragma unroll
    for (int i = 0; i < 4; i++) {
      int idx = i * 256 + tid;
      int row = idx >> 4, cp = idx & 15;
      int c = cp ^ (row & 15);
      gld16(vg + (size_t)row * S_ + kt * 128 + c * 8, &sVT[buf][(size_t)idx * 8]);
    }
  };

  bf16x8 bq[2][2];
#pragma unroll
  for (int nt = 0; nt < 2; nt++)
#pragma unroll
    for (int kk = 0; kk < 2; kk++)
      bq[nt][kk] =
          *(const bf16x8*)(qg + (size_t)(wid * 32 + nt * 16 + lr) * ldq + kk * 32 + quad * 8);

  float fs[2];
#pragma unroll
  for (int nt = 0; nt < 2; nt++) {
    int q = qb * 128 + wid * 32 + nt * 16 + lr;
    fs[nt] = TTM ? scale : scale * twn[b * S_ + q];
  }
  f32x4 O[2][4];
#pragma unroll
  for (int nt = 0; nt < 2; nt++)
#pragma unroll
    for (int dt = 0; dt < 4; dt++) O[nt][dt] = f32x4{0.f, 0.f, 0.f, 0.f};
  float lrow[2] = {0.f, 0.f};

  stage(0, 0);
  __syncthreads();

  for (int kt = 0; kt < 8; kt++) {
    const int cur = kt & 1;
    if (kt < 7) stage(kt + 1, cur ^ 1);
    const short* sKc = sK[cur];
    const short* sVc = sVT[cur];

    f32x4 Sa[8][2];
#pragma unroll
    for (int mt = 0; mt < 8; mt++)
#pragma unroll
      for (int nt = 0; nt < 2; nt++) Sa[mt][nt] = f32x4{0.f, 0.f, 0.f, 0.f};
#pragma unroll
    for (int mt = 0; mt < 8; mt++)
#pragma unroll
      for (int kk = 0; kk < 2; kk++) {
        int row = mt * 16 + lr;
        int cp = (kk * 4 + quad) ^ (lr & 7);
        bf16x8 ak = *(const bf16x8*)(sKc + row * 64 + cp * 8);
#pragma unroll
        for (int nt = 0; nt < 2; nt++)
          Sa[mt][nt] = __builtin_amdgcn_mfma_f32_16x16x32_bf16(ak, bq[nt][kk], Sa[mt][nt], 0, 0, 0);
      }

    // P = exp(score) (no max shift — bounded), accumulate l
    bf16x4 Pf[8][2];
#pragma unroll
    for (int nt = 0; nt < 2; nt++) {
      float ls = 0.f;
#pragma unroll
      for (int mt = 0; mt < 8; mt++) {
        float p0 = __expf(Sa[mt][nt][0] * fs[nt]);
        float p1 = __expf(Sa[mt][nt][1] * fs[nt]);
        float p2 = __expf(Sa[mt][nt][2] * fs[nt]);
        float p3 = __expf(Sa[mt][nt][3] * fs[nt]);
        ls += (p0 + p1) + (p2 + p3);
        __hip_bfloat16 h0 = __float2bfloat16(p0), h1 = __float2bfloat16(p1);
        __hip_bfloat16 h2 = __float2bfloat16(p2), h3 = __float2bfloat16(p3);
        bf16x4 pk;
        pk[0] = *(short*)&h0; pk[1] = *(short*)&h1;
        pk[2] = *(short*)&h2; pk[3] = *(short*)&h3;
        Pf[mt][nt] = pk;
      }
      ls += __shfl_xor(ls, 16);
      ls += __shfl_xor(ls, 32);
      lrow[nt] += ls;
    }

#pragma unroll
    for (int mt = 0; mt < 8; mt++)
#pragma unroll
      for (int dt = 0; dt < 4; dt++) {
        int row = dt * 16 + lr;
        int cp = (2 * mt + (quad >> 1)) ^ lr;
        bf16x4 bv = *(const bf16x4*)(sVc + row * 128 + cp * 8 + (quad & 1) * 4);
#pragma unroll
        for (int nt = 0; nt < 2; nt++) O[nt][dt] = pv_mfma(Pf[mt][nt], bv, O[nt][dt]);
      }

    __syncthreads();
  }

#pragma unroll
  for (int nt = 0; nt < 2; nt++)
#pragma unroll
    for (int r = 0; r < 4; r++) {
      float li = __shfl(lrow[nt], quad * 4 + r);
      float inv = 1.f / li;
      int q = qb * 128 + wid * 32 + nt * 16 + quad * 4 + r;
      __hip_bfloat16* op = ctx + ((size_t)(b * S_) + q) * H_ + h * 64 + lr;
#pragma unroll
      for (int dt = 0; dt < 4; dt++)
        op[dt * 16] = __float2bfloat16(O[nt][dt][r] * inv);
    }
}

// ---------------- MFMA wt-projection + LN(16) + sigmoid -> T0 ----------------
__global__ __launch_bounds__(256) void wtproj_k(const __hip_bfloat16* __restrict__ mctx,
                                                const float* __restrict__ weff,
                                                const float* __restrict__ g,
                                                const float* __restrict__ be,
                                                float* __restrict__ T0) {
  __shared__ float sC[4][256];
  const int tid = threadIdx.x, lane = tid & 63, wid = tid >> 6;
  const int lr = lane & 15, quad = lane >> 4;
  const int bs0 = blockIdx.x * 16;
  const short* aG = (const short*)mctx + (size_t)(bs0 + lr) * H_ + wid * 256;
  const float* bG = weff + (size_t)lr * H_ + wid * 256;
  f32x4 acc = f32x4{0.f, 0.f, 0.f, 0.f};
#pragma unroll
  for (int it = 0; it < 8; it++) {
    bf16x8 a = *(const bf16x8*)(aG + it * 32 + quad * 8);
    float4 b0 = *(const float4*)(bG + it * 32 + quad * 8);
    float4 b1 = *(const float4*)(bG + it * 32 + quad * 8 + 4);
    bf16x8 bb;
#pragma unroll
    for (int j = 0; j < 4; j++) {
      __hip_bfloat16 c0 = __float2bfloat16((&b0.x)[j]);
      __hip_bfloat16 c1 = __float2bfloat16((&b1.x)[j]);
      bb[j] = *(short*)&c0;
      bb[4 + j] = *(short*)&c1;
    }
    acc = __builtin_amdgcn_mfma_f32_16x16x32_bf16(a, bb, acc, 0, 0, 0);
  }
#pragma unroll
  for (int r = 0; r < 4; r++) sC[wid][(quad * 4 + r) * 16 + lr] = acc[r];
  __syncthreads();
  float tot = sC[0][tid] + sC[1][tid] + sC[2][tid] + sC[3][tid];
  const int n = tid & 15;
  float mean = tot;
#pragma unroll
  for (int o = 1; o < 16; o <<= 1) mean += __shfl_xor(mean, o);
  mean *= (1.f / 16.f);
  float d = tot - mean;
  float var = d * d;
#pragma unroll
  for (int o = 1; o < 16; o <<= 1) var += __shfl_xor(var, o);
  var *= (1.f / 16.f);
  float z = d * rsqrtf(var + 1e-5f) * g[n] + be[n];
  float t = 1.f / (1.f + expf(-z));
  T0[(size_t)blockIdx.x * 256 + tid] = 1.f + 0.1f * (t - 0.5f);
}

// ---------------- thp: sigmoid(gelu(LN(T0 @ thp_w^T + b))) ----------------
__global__ __launch_bounds__(256) void thp_k(const float* __restrict__ T0,
                                             const float* __restrict__ w,
                                             const float* __restrict__ bb,
                                             const float* __restrict__ g,
                                             const float* __restrict__ be,
                                             __hip_bfloat16* __restrict__ Tb,
                                             float* __restrict__ t0out) {
  __shared__ float sh[4];
  __shared__ float t0s[16];
  const int bs = blockIdx.x, tid = threadIdx.x;
  if (tid < 16) t0s[tid] = T0[(size_t)bs * 16 + tid];
  __syncthreads();
  float y[4];
#pragma unroll
  for (int i = 0; i < 4; i++) {
    int hh = tid + i * 256;
    const float* wr = w + (size_t)hh * 16;
    float a = bb[hh];
#pragma unroll
    for (int n = 0; n < 16; n++) a += t0s[n] * wr[n];
    y[i] = a;
  }
  float mean = bred_sum(y[0] + y[1] + y[2] + y[3], sh) * (1.f / 1024.f);
  float q = 0.f;
#pragma unroll
  for (int i = 0; i < 4; i++) { float d = y[i] - mean; q += d * d; }
  float var = bred_sum(q, sh) * (1.f / 1024.f);
  const float rs = rsqrtf(var + 1e-5f);
#pragma unroll
  for (int i = 0; i < 4; i++) {
    int hh = tid + i * 256;
    float z = (y[i] - mean) * rs * g[hh] + be[hh];
    float t = 1.f / (1.f + expf(-geluf(z)));
    Tb[(size_t)bs * H_ + hh] = __float2bfloat16(t);
    if (hh == 0) t0out[bs] = t;
  }
}

// ---------------- fused temp_net iterations 1+2 ----------------
__global__ __launch_bounds__(256) void hlnrd2_k(const float* __restrict__ xw1a,
                                                const float* __restrict__ tbwf,
                                                const float* __restrict__ rsum,
                                                const float* __restrict__ b1,
                                                const float* __restrict__ g,
                                                const float* __restrict__ be,
                                                const float* __restrict__ w2,
                                                const float* __restrict__ b2,
                                                float* __restrict__ t1out,
                                                float* __restrict__ t2out) {
  __shared__ float sh[4];
  const int bs = blockIdx.x, tid = threadIdx.x;
  float xa[4], bv[4], y[4];
#pragma unroll
  for (int i = 0; i < 4; i++) {
    int hh = tid + i * 256;
    xa[i] = xw1a[(size_t)bs * H_ + hh];
    bv[i] = b1[hh];
    y[i] = tbwf[(size_t)bs * H_ + hh] + bv[i];
  }
  float T1, T2;
#pragma unroll
  for (int iter = 0; iter < 2; iter++) {
    float mean = bred_sum(y[0] + y[1] + y[2] + y[3], sh) * (1.f / 1024.f);
    float q = 0.f;
#pragma unroll
    for (int i = 0; i < 4; i++) { float d = y[i] - mean; q += d * d; }
    float var = bred_sum(q, sh) * (1.f / 1024.f);
    const float rs = rsqrtf(var + 1e-5f);
    float s = 0.f;
#pragma unroll
    for (int i = 0; i < 4; i++) {
      int hh = tid + i * 256;
      float z = (y[i] - mean) * rs * g[hh] + be[hh];
      s += geluf(z) * w2[hh];
    }
    s = bred_sum(s, sh);
    float d = s + b2[0];
    float t = 1.f / (1.f + expf(-d));
    t = 1.f / (1.f + expf(-t));
    if (iter == 0) {
      T1 = t;
#pragma unroll
      for (int i = 0; i < 4; i++) {
        int hh = tid + i * 256;
        y[i] = xa[i] + T1 * rsum[hh] + bv[i];
      }
    } else {
      T2 = t;
    }
  }
  if (tid == 0) { t1out[bs] = T1; t2out[bs] = T2; }
}

// ---------------- global stats -> twn; scale_temps output ----------------
__global__ __launch_bounds__(256) void stats_k(const float* __restrict__ t0,
                                               const float* __restrict__ t1,
                                               const float* __restrict__ t2,
                                               float* __restrict__ twn,
                                               float* __restrict__ out2) {
  __shared__ float sh[4];
  const int tid = threadIdx.x;
  float s = 0.f;
  for (int i = tid; i < BS_; i += 256) s += (t0[i] + t1[i] + t2[i]) * (1.f / 3.f);
  const float mu = bred_sum(s, sh) * (1.f / (float)BS_);
  float q = 0.f;
  for (int i = tid; i < BS_; i += 256) {
    float tw = (t0[i] + t1[i] + t2[i]) * (1.f / 3.f);
    float d = tw - mu;
    q += d * d;
  }
  const float var = bred_sum(q, sh) * (1.f / (float)BS_);
  const float stdu = sqrtf(var);
  const float inv = 1.f / (stdu + 1.1920929e-07f);
  for (int i = tid; i < BS_; i += 256) {
    float tw = (t0[i] + t1[i] + t2[i]) * (1.f / 3.f);
    twn[i] = 1.f + (tw - mu) * inv;
  }
  for (int i = tid; i < 3 * BS_; i += 256) {
    int b = i / 3072, r = i - b * 3072;
    int j = r >> 10, ss = r & 1023;
    const float* tp = (j == 0) ? t0 : ((j == 1) ? t1 : t2);
    out2[i] = tp[b * S_ + ss];
  }
}

// =====================================================================
extern "C" void kernel_launch(void* const* d_in, const int* in_sizes, int n_in,
                              void* d_out, int out_size, void* d_ws, size_t ws_size,
                              hipStream_t stream) {
  (void)in_sizes; (void)n_in; (void)out_size; (void)ws_size;
  const float* x     = (const float*)d_in[0];
  const float* wq    = (const float*)d_in[1];
  const float* wk    = (const float*)d_in[2];
  const float* wv    = (const float*)d_in[3];
  const float* wo    = (const float*)d_in[4];
  const float* w_in  = (const float*)d_in[5];
  const float* w_out = (const float*)d_in[6];
  const float* wt    = (const float*)d_in[7];
  const float* ttm_g = (const float*)d_in[8];
  const float* ttm_b = (const float*)d_in[9];
  const float* thp_w = (const float*)d_in[10];
  const float* thp_b = (const float*)d_in[11];
  const float* thp_g = (const float*)d_in[12];
  const float* thp_e = (const float*)d_in[13];
  const float* w1    = (const float*)d_in[14];
  const float* b1    = (const float*)d_in[15];
  const float* tn_g  = (const float*)d_in[16];
  const float* tn_e  = (const float*)d_in[17];
  const float* w2    = (const float*)d_in[18];
  const float* b2    = (const float*)d_in[19];

  char* ws = (char*)d_ws;
  size_t off = 0;
  auto alloc = [&](size_t bytes) {
    void* p = ws + off;
    off = (off + bytes + 255) & ~(size_t)255;
    return p;
  };

  __hip_bfloat16* xb    = (__hip_bfloat16*)alloc((size_t)BS_ * H_ * 2);
  __hip_bfloat16* wcat  = (__hip_bfloat16*)alloc((size_t)H6_ * H_ * 2);
  __hip_bfloat16* wob   = (__hip_bfloat16*)alloc((size_t)H_ * H_ * 2);
  __hip_bfloat16* w1b   = (__hip_bfloat16*)alloc((size_t)H_ * 2 * H_ * 2);
  __hip_bfloat16* qkv2  = (__hip_bfloat16*)alloc((size_t)BS_ * H6_ * 2);
  __hip_bfloat16* vt2   = (__hip_bfloat16*)alloc((size_t)128 * DH_ * S_ * 2);
  __hip_bfloat16* mctxb = (__hip_bfloat16*)alloc((size_t)BS_ * H_ * 2);
  __hip_bfloat16* tob   = (__hip_bfloat16*)alloc((size_t)BS_ * H_ * 2);
  float* weff  = (float*)alloc((size_t)NH_ * H_ * 4);
  float* T0    = (float*)alloc((size_t)BS_ * NH_ * 4);
  float* xw1a  = (float*)alloc((size_t)BS_ * H_ * 4);
  float* tbw   = (float*)alloc((size_t)BS_ * H_ * 4);
  float* temps = (float*)alloc((size_t)3 * BS_ * 4);
  float* twn   = (float*)alloc((size_t)BS_ * 4);
  float* rsum  = (float*)alloc((size_t)H_ * 4);

  const float scale = 0.125f;
  dim3 blk(256);

  // ---- prep: casts + weff + rowsum (1 dispatch) ----
  PrepArgs pa;
  pa.s[0] = {x, (unsigned short*)xb, BS_ * H_};
  pa.s[1] = {w_in, (unsigned short*)wcat, 3 * H_ * H_};
  pa.s[2] = {wq, (unsigned short*)wcat + (size_t)3 * H_ * H_, H_ * H_};
  pa.s[3] = {wk, (unsigned short*)wcat + (size_t)4 * H_ * H_, H_ * H_};
  pa.s[4] = {wv, (unsigned short*)wcat + (size_t)5 * H_ * H_, H_ * H_};
  pa.s[5] = {wo, (unsigned short*)wob, H_ * H_};
  pa.s[6] = {w1, (unsigned short*)w1b, 2 * H_ * H_};
  pa.wt = wt; pa.wout = w_out; pa.weff = weff; pa.w1 = w1; pa.rsum = rsum;
  prep_k<<<dim3((BS_ * H_ + 1023) / 1024, 9), blk, 0, stream>>>(pa);

  // ---- merged qkv GEMM (writes Q/K rows + V transposed) ----
  gemm_qkv_k<<<dim3(H6_ / 128, BS_ / 128), blk, 0, stream>>>(xb, wcat, qkv2, vt2);

  // ---- ttm attention -> mctx; wt-projection -> T0; thp -> T_base ----
  flash_k<true><<<dim3(64, 8), blk, 0, stream>>>(qkv2, vt2, (const float*)nullptr, mctxb,
                                                 scale, H6_);
  wtproj_k<<<BS_ / 16, blk, 0, stream>>>(mctxb, weff, ttm_g, ttm_b, T0);
  thp_k<<<BS_, blk, 0, stream>>>(T0, thp_w, thp_b, thp_g, thp_e, tob, temps);

  // ---- temp_net: dual-A GEMM (K=2048) + fused iterations + stats ----
  gemm_bt<4, 2, 2, 2, true><<<dim3(H_ / 64, BS_ / 128), blk, 0, stream>>>(
      xb, w1b, tbw, 2 * H_, H_, 2 * H_, H_, tob, xw1a, H_);
  hlnrd2_k<<<BS_, blk, 0, stream>>>(xw1a, tbw, rsum, b1, tn_g, tn_e, w2, b2,
                                    temps + BS_, temps + 2 * BS_);
  stats_k<<<1, blk, 0, stream>>>(temps, temps + BS_, temps + 2 * BS_, twn,
                                 (float*)d_out + (size_t)BS_ * H_);

  // ---- main attention + out-proj ----
  flash_k<false><<<dim3(64, 8), blk, 0, stream>>>(qkv2 + 3 * H_,
                                                  vt2 + (size_t)64 * DH_ * S_, twn, mctxb,
                                                  scale, H6_);
  gemm_bt<4, 2, 2, 2, false><<<dim3(H_ / 64, BS_ / 128), blk, 0, stream>>>(
      mctxb, wob, (float*)d_out, H_, H_, H_, H_, nullptr, nullptr, 0);
}

// Round 7
// 401.886 us; speedup vs baseline: 1.3059x; 1.3059x over previous
//
#include <hip/hip_runtime.h>
#include <hip/hip_bf16.h>

#define DEV __device__ __forceinline__

typedef short bf16x8 __attribute__((ext_vector_type(8)));
typedef short bf16x4 __attribute__((ext_vector_type(4)));
typedef float f32x4 __attribute__((ext_vector_type(4)));

static constexpr int B_  = 4;
static constexpr int S_  = 1024;
static constexpr int H_  = 1024;
static constexpr int NH_ = 16;
static constexpr int DH_ = 64;
static constexpr int BS_ = B_ * S_;   // 4096
static constexpr int H6_ = 6 * H_;    // 6144

// ---------------- async global->LDS (16B per lane) ----------------
DEV void gld16(const void* g, void* l) {
  __builtin_amdgcn_global_load_lds(
      (__attribute__((address_space(1))) void*)(unsigned long long)g,
      (__attribute__((address_space(3))) void*)(unsigned)(unsigned long long)l,
      16, 0, 0);
}

// 16x16x16 bf16 MFMA (A-frag layout matches C-layout of transposed scores)
DEV f32x4 pv_mfma(bf16x4 a, bf16x4 b, f32x4 c) {
#if __has_builtin(__builtin_amdgcn_mfma_f32_16x16x16bf16_1k)
  return __builtin_amdgcn_mfma_f32_16x16x16bf16_1k(a, b, c, 0, 0, 0);
#else
  asm volatile("v_mfma_f32_16x16x16_bf16 %0, %1, %2, %0" : "+v"(c) : "v"(a), "v"(b));
  return c;
#endif
}

// ---------------- reductions (blockDim == 256) ----------------
DEV float wred_sum(float v) {
#pragma unroll
  for (int o = 32; o; o >>= 1) v += __shfl_xor(v, o);
  return v;
}
DEV float bred_sum(float v, float* sh) {
  v = wred_sum(v);
  const int tid = threadIdx.x;
  if ((tid & 63) == 0) sh[tid >> 6] = v;
  __syncthreads();
  v = sh[0] + sh[1] + sh[2] + sh[3];
  __syncthreads();
  return v;
}
DEV float geluf(float x) { return 0.5f * x * (1.f + erff(x * 0.70710678118654752f)); }

// ---------------- prep: casts + weff + rowsum in ONE dispatch ----------------
struct CastSeg { const float* src; unsigned short* dst; int n; };
struct PrepArgs {
  CastSeg s[7];
  const float* wt; const float* wout; float* weff;
  const float* w1; float* rsum;
};
__global__ __launch_bounds__(256) void prep_k(PrepArgs a) {
  const int y = blockIdx.y, tid = threadIdx.x;
  if (y < 7) {
    const CastSeg g = a.s[y];
    int i = (blockIdx.x * 256 + tid) * 4;
    if (i >= g.n) return;
    float4 v = *(const float4*)(g.src + i);
    __hip_bfloat16 o0 = __float2bfloat16(v.x), o1 = __float2bfloat16(v.y);
    __hip_bfloat16 o2 = __float2bfloat16(v.z), o3 = __float2bfloat16(v.w);
    ushort4 o;
    o.x = *(unsigned short*)&o0; o.y = *(unsigned short*)&o1;
    o.z = *(unsigned short*)&o2; o.w = *(unsigned short*)&o3;
    *(ushort4*)(g.dst + i) = o;
  } else if (y == 7) {
    // weff[n,h] += sum over o-chunk of wt[n,o]*wout[o,h]
    // 256 blocks: bx&15 = h-block (64 h), bx>>4 = o-chunk (64 o). atomic combine.
    if (blockIdx.x >= 256) return;
    const int h = (blockIdx.x & 15) * 64 + (tid & 63), ng = tid >> 6;
    const int o0 = (blockIdx.x >> 4) * 64;
    float acc[4] = {0.f, 0.f, 0.f, 0.f};
#pragma unroll 8
    for (int o = o0; o < o0 + 64; o++) {
      float wv = a.wout[(size_t)o * H_ + h];
#pragma unroll
      for (int i = 0; i < 4; i++) acc[i] += a.wt[(size_t)(ng * 4 + i) * H_ + o] * wv;
    }
#pragma unroll
    for (int i = 0; i < 4; i++) atomicAdd(&a.weff[(size_t)(ng * 4 + i) * H_ + h], acc[i]);
  } else {
    // rowsum of W1b (fp32 exact)
    if (blockIdx.x >= 256) return;
    const int row = blockIdx.x * 4 + (tid >> 6), lane = tid & 63;
    float s = 0.f;
#pragma unroll
    for (int j = 0; j < 16; j++) s += a.w1[(size_t)row * 2048 + 1024 + lane + j * 64];
    s = wred_sum(s);
    if (lane == 0) a.rsum[row] = s;
  }
}

// ---------------- QKV GEMM (N=6144) with V-transposed epilogue ----------------
__global__ __launch_bounds__(256) void gemm_qkv_k(
    const __hip_bfloat16* __restrict__ Ap, const __hip_bfloat16* __restrict__ Wp,
    __hip_bfloat16* __restrict__ Cp, __hip_bfloat16* __restrict__ vt2) {
  constexpr int BK = 32;
  __shared__ __align__(16) short smem[8448];  // sA(4096)+sB(4096) aliased w/ sT(8448)
  short* sA = smem;
  short* sB = smem + 4096;
  short* sT = smem;
  const int tid = threadIdx.x;
  const int wave = tid >> 6, lane = tid & 63;
  const int wm = wave >> 1, wn = wave & 1;
  const int lr = lane & 15, kq = lane >> 4;
  const int bx = blockIdx.x, by = blockIdx.y;
  const short* Ab = (const short*)Ap + (long long)by * 128 * H_;
  const short* Wb = (const short*)Wp + (long long)bx * 128 * H_;

  f32x4 acc[4][4];
#pragma unroll
  for (int i = 0; i < 4; i++)
#pragma unroll
    for (int j = 0; j < 4; j++) acc[i][j] = f32x4{0.f, 0.f, 0.f, 0.f};

  for (int k0 = 0; k0 < H_; k0 += BK) {
#pragma unroll
    for (int r = 0; r < 2; r++) {
      int idx = r * 256 + tid;
      gld16(Ab + (long long)(idx >> 2) * H_ + k0 + (idx & 3) * 8, sA + (size_t)idx * 8);
    }
#pragma unroll
    for (int r = 0; r < 2; r++) {
      int idx = r * 256 + tid;
      gld16(Wb + (long long)(idx >> 2) * H_ + k0 + (idx & 3) * 8, sB + (size_t)idx * 8);
    }
    __syncthreads();
    bf16x8 af[4], bfr[4];
#pragma unroll
    for (int i = 0; i < 4; i++)
      af[i] = *(const bf16x8*)(sA + (wm * 64 + i * 16 + lr) * BK + kq * 8);
#pragma unroll
    for (int j = 0; j < 4; j++)
      bfr[j] = *(const bf16x8*)(sB + (wn * 64 + j * 16 + lr) * BK + kq * 8);
#pragma unroll
    for (int i = 0; i < 4; i++)
#pragma unroll
      for (int j = 0; j < 4; j++)
        acc[i][j] = __builtin_amdgcn_mfma_f32_16x16x32_bf16(af[i], bfr[j], acc[i][j], 0, 0, 0);
    __syncthreads();
  }

  const bool isV = (bx >= 16 && bx < 24) || (bx >= 40);
  if (!isV) {
    const long long row0 = (long long)by * 128 + wm * 64 + kq * 4;
    const long long col0 = (long long)bx * 128 + wn * 64 + lr;
#pragma unroll
    for (int i = 0; i < 4; i++)
#pragma unroll
      for (int j = 0; j < 4; j++)
#pragma unroll
        for (int r = 0; r < 4; r++)
          Cp[(row0 + i * 16 + r) * H6_ + col0 + j * 16] = __float2bfloat16(acc[i][j][r]);
  } else {
    const int sel = bx >= 40;
    const int h0 = (bx - (sel ? 40 : 16)) * 2;
    const int b = by >> 3, s0 = (by & 7) * 128;
#pragma unroll
    for (int hh = 0; hh < 2; hh++) {
      __syncthreads();
      if (wn == hh) {
#pragma unroll
        for (int i = 0; i < 4; i++)
#pragma unroll
          for (int j = 0; j < 4; j++)
#pragma unroll
            for (int r = 0; r < 4; r++) {
              __hip_bfloat16 v = __float2bfloat16(acc[i][j][r]);
              sT[(j * 16 + lr) * 132 + wm * 64 + i * 16 + kq * 4 + r] = *(short*)&v;
            }
      }
      __syncthreads();
      const int bh2 = sel * 64 + b * 16 + h0 + hh;
      short* dst = (short*)vt2 + (size_t)bh2 * DH_ * S_ + s0;
#pragma unroll
      for (int c = 0; c < 8; c++) {
        int flat = c * 256 + tid;
        int d = flat >> 5, s4 = (flat & 31) * 4;
        *(short4*)(dst + (size_t)d * S_ + s4) = *(short4*)(sT + d * 132 + s4);
      }
    }
  }
}

// ---------------- generic MFMA GEMM (fp32 out), MID dual-A variant ----------------
template <int MT, int NT, int WR, int WC, bool MID>
__global__ __launch_bounds__(256) void gemm_bt(
    const __hip_bfloat16* __restrict__ Ap, const __hip_bfloat16* __restrict__ Wp,
    float* __restrict__ Cp, int K, int lda, int ldw, int ldc,
    const __hip_bfloat16* __restrict__ Ap2, float* __restrict__ Cmid, int kmid) {
  constexpr int BM = WR * MT * 16;
  constexpr int BN = WC * NT * 16;
  constexpr int BK = 32;
  __shared__ __align__(16) short sA[BM * BK];
  __shared__ __align__(16) short sB[BN * BK];
  const int tid = threadIdx.x;
  const int wave = tid >> 6, lane = tid & 63;
  const int wm = wave / WC, wn = wave % WC;
  const int lr = lane & 15, kq = lane >> 4;
  const short* Ab = (const short*)Ap + (long long)blockIdx.y * BM * lda;
  const short* Ab2 = MID ? (const short*)Ap2 + (long long)blockIdx.y * BM * lda : nullptr;
  const short* Wb = (const short*)Wp + (long long)blockIdx.x * BN * ldw;
  const long long row0 = (long long)blockIdx.y * BM + wm * MT * 16 + kq * 4;
  const long long col0 = (long long)blockIdx.x * BN + wn * NT * 16 + lr;

  f32x4 acc[MT][NT];
#pragma unroll
  for (int i = 0; i < MT; i++)
#pragma unroll
    for (int j = 0; j < NT; j++) acc[i][j] = f32x4{0.f, 0.f, 0.f, 0.f};

  for (int k0 = 0; k0 < K; k0 += BK) {
    const short* Asrc;
    int ka;
    if (MID && k0 >= kmid) { Asrc = Ab2; ka = k0 - kmid; }
    else { Asrc = Ab; ka = k0; }
#pragma unroll
    for (int r = 0; r < BM / 64; r++) {
      int idx = r * 256 + tid;
      gld16(Asrc + (long long)(idx >> 2) * lda + ka + (idx & 3) * 8, sA + (size_t)idx * 8);
    }
#pragma unroll
    for (int r = 0; r < BN / 64; r++) {
      int idx = r * 256 + tid;
      gld16(Wb + (long long)(idx >> 2) * ldw + k0 + (idx & 3) * 8, sB + (size_t)idx * 8);
    }
    __syncthreads();
    bf16x8 af[MT], bfr[NT];
#pragma unroll
    for (int i = 0; i < MT; i++)
      af[i] = *(const bf16x8*)(sA + (wm * MT * 16 + i * 16 + lr) * BK + kq * 8);
#pragma unroll
    for (int j = 0; j < NT; j++)
      bfr[j] = *(const bf16x8*)(sB + (wn * NT * 16 + j * 16 + lr) * BK + kq * 8);
#pragma unroll
    for (int i = 0; i < MT; i++)
#pragma unroll
      for (int j = 0; j < NT; j++)
        acc[i][j] = __builtin_amdgcn_mfma_f32_16x16x32_bf16(af[i], bfr[j], acc[i][j], 0, 0, 0);
    if constexpr (MID) {
      if (k0 + BK == kmid) {
#pragma unroll
        for (int i = 0; i < MT; i++)
#pragma unroll
          for (int j = 0; j < NT; j++)
#pragma unroll
            for (int r = 0; r < 4; r++)
              Cmid[(row0 + i * 16 + r) * ldc + col0 + j * 16] = acc[i][j][r];
      }
    }
    __syncthreads();
  }
#pragma unroll
  for (int i = 0; i < MT; i++)
#pragma unroll
    for (int j = 0; j < NT; j++)
#pragma unroll
      for (int r = 0; r < 4; r++)
        Cp[(row0 + i * 16 + r) * ldc + col0 + j * 16] = acc[i][j][r];
}

// ---------------- fused flash attention (no online max: scores bounded) ----------------
template <bool TTM>
__global__ __launch_bounds__(256) void flash_k(
    const __hip_bfloat16* __restrict__ qkvB,
    const __hip_bfloat16* __restrict__ vt,
    const float* __restrict__ twn,
    __hip_bfloat16* __restrict__ ctx,
    float scale, int ldq) {
  __shared__ __align__(16) short sK[2][128 * 64];
  __shared__ __align__(16) short sVT[2][64 * 128];
  const int bh = blockIdx.x, b = bh >> 4, h = bh & 15;
  const int qb = blockIdx.y;
  const int tid = threadIdx.x, lane = tid & 63, wid = tid >> 6;
  const int lr = lane & 15, quad = lane >> 4;
  const short* qg = (const short*)qkvB + ((size_t)(b * S_) + qb * 128) * ldq + h * 64;
  const short* kg = (const short*)qkvB + (size_t)b * S_ * ldq + H_ + h * 64;
  const short* vg = (const short*)vt + (size_t)bh * DH_ * S_;

  auto stage = [&](int kt, int buf) {
#pragma unroll
    for (int i = 0; i < 4; i++) {
      int idx = i * 256 + tid;
      int row = idx >> 3, cp = idx & 7;
      int c = cp ^ (row & 7);
      gld16(kg + (size_t)(kt * 128 + row) * ldq + c * 8, &sK[buf][(size_t)idx * 8]);
    }
#pragma unroll
    for (int i = 0; i < 4; i++) {
      int idx = i * 256 + tid;
      int row = idx >> 4, cp = idx & 15;
      int c = cp ^ (row & 15);
      gld16(vg + (size_t)row * S_ + kt * 128 + c * 8, &sVT[buf][(size_t)idx * 8]);
    }
  };

  bf16x8 bq[2][2];
#pragma unroll
  for (int nt = 0; nt < 2; nt++)
#pragma unroll
    for (int kk = 0; kk < 2; kk++)
      bq[nt][kk] =
          *(const bf16x8*)(qg + (size_t)(wid * 32 + nt * 16 + lr) * ldq + kk * 32 + quad * 8);

  float fs[2];
#pragma unroll
  for (int nt = 0; nt < 2; nt++) {
    int q = qb * 128 + wid * 32 + nt * 16 + lr;
    fs[nt] = TTM ? scale : scale * twn[b * S_ + q];
  }
  f32x4 O[2][4];
#pragma unroll
  for (int nt = 0; nt < 2; nt++)
#pragma unroll
    for (int dt = 0; dt < 4; dt++) O[nt][dt] = f32x4{0.f, 0.f, 0.f, 0.f};
  float lrow[2] = {0.f, 0.f};

  stage(0, 0);
  __syncthreads();

  for (int kt = 0; kt < 8; kt++) {
    const int cur = kt & 1;
    if (kt < 7) stage(kt + 1, cur ^ 1);
    const short* sKc = sK[cur];
    const short* sVc = sVT[cur];

    f32x4 Sa[8][2];
#pragma unroll
    for (int mt = 0; mt < 8; mt++)
#pragma unroll
      for (int nt = 0; nt < 2; nt++) Sa[mt][nt] = f32x4{0.f, 0.f, 0.f, 0.f};
#pragma unroll
    for (int mt = 0; mt < 8; mt++)
#pragma unroll
      for (int kk = 0; kk < 2; kk++) {
        int row = mt * 16 + lr;
        int cp = (kk * 4 + quad) ^ (lr & 7);
        bf16x8 ak = *(const bf16x8*)(sKc + row * 64 + cp * 8);
#pragma unroll
        for (int nt = 0; nt < 2; nt++)
          Sa[mt][nt] = __builtin_amdgcn_mfma_f32_16x16x32_bf16(ak, bq[nt][kk], Sa[mt][nt], 0, 0, 0);
      }

    bf16x4 Pf[8][2];
#pragma unroll
    for (int nt = 0; nt < 2; nt++) {
      float ls = 0.f;
#pragma unroll
      for (int mt = 0; mt < 8; mt++) {
        float p0 = __expf(Sa[mt][nt][0] * fs[nt]);
        float p1 = __expf(Sa[mt][nt][1] * fs[nt]);
        float p2 = __expf(Sa[mt][nt][2] * fs[nt]);
        float p3 = __expf(Sa[mt][nt][3] * fs[nt]);
        ls += (p0 + p1) + (p2 + p3);
        __hip_bfloat16 h0 = __float2bfloat16(p0), h1 = __float2bfloat16(p1);
        __hip_bfloat16 h2 = __float2bfloat16(p2), h3 = __float2bfloat16(p3);
        bf16x4 pk;
        pk[0] = *(short*)&h0; pk[1] = *(short*)&h1;
        pk[2] = *(short*)&h2; pk[3] = *(short*)&h3;
        Pf[mt][nt] = pk;
      }
      ls += __shfl_xor(ls, 16);
      ls += __shfl_xor(ls, 32);
      lrow[nt] += ls;
    }

#pragma unroll
    for (int mt = 0; mt < 8; mt++)
#pragma unroll
      for (int dt = 0; dt < 4; dt++) {
        int row = dt * 16 + lr;
        int cp = (2 * mt + (quad >> 1)) ^ lr;
        bf16x4 bv = *(const bf16x4*)(sVc + row * 128 + cp * 8 + (quad & 1) * 4);
#pragma unroll
        for (int nt = 0; nt < 2; nt++) O[nt][dt] = pv_mfma(Pf[mt][nt], bv, O[nt][dt]);
      }

    __syncthreads();
  }

#pragma unroll
  for (int nt = 0; nt < 2; nt++)
#pragma unroll
    for (int r = 0; r < 4; r++) {
      float li = __shfl(lrow[nt], quad * 4 + r);
      float inv = 1.f / li;
      int q = qb * 128 + wid * 32 + nt * 16 + quad * 4 + r;
      __hip_bfloat16* op = ctx + ((size_t)(b * S_) + q) * H_ + h * 64 + lr;
#pragma unroll
      for (int dt = 0; dt < 4; dt++)
        op[dt * 16] = __float2bfloat16(O[nt][dt][r] * inv);
    }
}

// ---------------- MFMA wt-projection + LN(16) + sigmoid -> T0 ----------------
__global__ __launch_bounds__(256) void wtproj_k(const __hip_bfloat16* __restrict__ mctx,
                                                const float* __restrict__ weff,
                                                const float* __restrict__ g,
                                                const float* __restrict__ be,
                                                float* __restrict__ T0) {
  __shared__ float sC[4][256];
  const int tid = threadIdx.x, lane = tid & 63, wid = tid >> 6;
  const int lr = lane & 15, quad = lane >> 4;
  const int bs0 = blockIdx.x * 16;
  const short* aG = (const short*)mctx + (size_t)(bs0 + lr) * H_ + wid * 256;
  const float* bG = weff + (size_t)lr * H_ + wid * 256;
  f32x4 acc = f32x4{0.f, 0.f, 0.f, 0.f};
#pragma unroll
  for (int it = 0; it < 8; it++) {
    bf16x8 a = *(const bf16x8*)(aG + it * 32 + quad * 8);
    float4 b0 = *(const float4*)(bG + it * 32 + quad * 8);
    float4 b1 = *(const float4*)(bG + it * 32 + quad * 8 + 4);
    bf16x8 bb;
#pragma unroll
    for (int j = 0; j < 4; j++) {
      __hip_bfloat16 c0 = __float2bfloat16((&b0.x)[j]);
      __hip_bfloat16 c1 = __float2bfloat16((&b1.x)[j]);
      bb[j] = *(short*)&c0;
      bb[4 + j] = *(short*)&c1;
    }
    acc = __builtin_amdgcn_mfma_f32_16x16x32_bf16(a, bb, acc, 0, 0, 0);
  }
#pragma unroll
  for (int r = 0; r < 4; r++) sC[wid][(quad * 4 + r) * 16 + lr] = acc[r];
  __syncthreads();
  float tot = sC[0][tid] + sC[1][tid] + sC[2][tid] + sC[3][tid];
  const int n = tid & 15;
  float mean = tot;
#pragma unroll
  for (int o = 1; o < 16; o <<= 1) mean += __shfl_xor(mean, o);
  mean *= (1.f / 16.f);
  float d = tot - mean;
  float var = d * d;
#pragma unroll
  for (int o = 1; o < 16; o <<= 1) var += __shfl_xor(var, o);
  var *= (1.f / 16.f);
  float z = d * rsqrtf(var + 1e-5f) * g[n] + be[n];
  float t = 1.f / (1.f + expf(-z));
  T0[(size_t)blockIdx.x * 256 + tid] = 1.f + 0.1f * (t - 0.5f);
}

// ---------------- thp: sigmoid(gelu(LN(T0 @ thp_w^T + b))) ----------------
__global__ __launch_bounds__(256) void thp_k(const float* __restrict__ T0,
                                             const float* __restrict__ w,
                                             const float* __restrict__ bb,
                                             const float* __restrict__ g,
                                             const float* __restrict__ be,
                                             __hip_bfloat16* __restrict__ Tb,
                                             float* __restrict__ t0out) {
  __shared__ float sh[4];
  __shared__ float t0s[16];
  const int bs = blockIdx.x, tid = threadIdx.x;
  if (tid < 16) t0s[tid] = T0[(size_t)bs * 16 + tid];
  __syncthreads();
  float y[4];
#pragma unroll
  for (int i = 0; i < 4; i++) {
    int hh = tid + i * 256;
    const float* wr = w + (size_t)hh * 16;
    float a = bb[hh];
#pragma unroll
    for (int n = 0; n < 16; n++) a += t0s[n] * wr[n];
    y[i] = a;
  }
  float mean = bred_sum(y[0] + y[1] + y[2] + y[3], sh) * (1.f / 1024.f);
  float q = 0.f;
#pragma unroll
  for (int i = 0; i < 4; i++) { float d = y[i] - mean; q += d * d; }
  float var = bred_sum(q, sh) * (1.f / 1024.f);
  const float rs = rsqrtf(var + 1e-5f);
#pragma unroll
  for (int i = 0; i < 4; i++) {
    int hh = tid + i * 256;
    float z = (y[i] - mean) * rs * g[hh] + be[hh];
    float t = 1.f / (1.f + expf(-geluf(z)));
    Tb[(size_t)bs * H_ + hh] = __float2bfloat16(t);
    if (hh == 0) t0out[bs] = t;
  }
}

// ---------------- fused temp_net iterations 1+2 ----------------
__global__ __launch_bounds__(256) void hlnrd2_k(const float* __restrict__ xw1a,
                                                const float* __restrict__ tbwf,
                                                const float* __restrict__ rsum,
                                                const float* __restrict__ b1,
                                                const float* __restrict__ g,
                                                const float* __restrict__ be,
                                                const float* __restrict__ w2,
                                                const float* __restrict__ b2,
                                                float* __restrict__ t1out,
                                                float* __restrict__ t2out) {
  __shared__ float sh[4];
  const int bs = blockIdx.x, tid = threadIdx.x;
  float xa[4], bv[4], y[4];
#pragma unroll
  for (int i = 0; i < 4; i++) {
    int hh = tid + i * 256;
    xa[i] = xw1a[(size_t)bs * H_ + hh];
    bv[i] = b1[hh];
    y[i] = tbwf[(size_t)bs * H_ + hh] + bv[i];
  }
  float T1, T2;
#pragma unroll
  for (int iter = 0; iter < 2; iter++) {
    float mean = bred_sum(y[0] + y[1] + y[2] + y[3], sh) * (1.f / 1024.f);
    float q = 0.f;
#pragma unroll
    for (int i = 0; i < 4; i++) { float d = y[i] - mean; q += d * d; }
    float var = bred_sum(q, sh) * (1.f / 1024.f);
    const float rs = rsqrtf(var + 1e-5f);
    float s = 0.f;
#pragma unroll
    for (int i = 0; i < 4; i++) {
      int hh = tid + i * 256;
      float z = (y[i] - mean) * rs * g[hh] + be[hh];
      s += geluf(z) * w2[hh];
    }
    s = bred_sum(s, sh);
    float d = s + b2[0];
    float t = 1.f / (1.f + expf(-d));
    t = 1.f / (1.f + expf(-t));
    if (iter == 0) {
      T1 = t;
#pragma unroll
      for (int i = 0; i < 4; i++) {
        int hh = tid + i * 256;
        y[i] = xa[i] + T1 * rsum[hh] + bv[i];
      }
    } else {
      T2 = t;
    }
  }
  if (tid == 0) { t1out[bs] = T1; t2out[bs] = T2; }
}

// ---------------- global stats -> twn; scale_temps output ----------------
__global__ __launch_bounds__(256) void stats_k(const float* __restrict__ t0,
                                               const float* __restrict__ t1,
                                               const float* __restrict__ t2,
                                               float* __restrict__ twn,
                                               float* __restrict__ out2) {
  __shared__ float sh[4];
  const int tid = threadIdx.x;
  float s = 0.f;
  for (int i = tid; i < BS_; i += 256) s += (t0[i] + t1[i] + t2[i]) * (1.f / 3.f);
  const float mu = bred_sum(s, sh) * (1.f / (float)BS_);
  float q = 0.f;
  for (int i = tid; i < BS_; i += 256) {
    float tw = (t0[i] + t1[i] + t2[i]) * (1.f / 3.f);
    float d = tw - mu;
    q += d * d;
  }
  const float var = bred_sum(q, sh) * (1.f / (float)BS_);
  const float stdu = sqrtf(var);
  const float inv = 1.f / (stdu + 1.1920929e-07f);
  for (int i = tid; i < BS_; i += 256) {
    float tw = (t0[i] + t1[i] + t2[i]) * (1.f / 3.f);
    twn[i] = 1.f + (tw - mu) * inv;
  }
  for (int i = tid; i < 3 * BS_; i += 256) {
    int b = i / 3072, r = i - b * 3072;
    int j = r >> 10, ss = r & 1023;
    const float* tp = (j == 0) ? t0 : ((j == 1) ? t1 : t2);
    out2[i] = tp[b * S_ + ss];
  }
}

// =====================================================================
extern "C" void kernel_launch(void* const* d_in, const int* in_sizes, int n_in,
                              void* d_out, int out_size, void* d_ws, size_t ws_size,
                              hipStream_t stream) {
  (void)in_sizes; (void)n_in; (void)out_size; (void)ws_size;
  const float* x     = (const float*)d_in[0];
  const float* wq    = (const float*)d_in[1];
  const float* wk    = (const float*)d_in[2];
  const float* wv    = (const float*)d_in[3];
  const float* wo    = (const float*)d_in[4];
  const float* w_in  = (const float*)d_in[5];
  const float* w_out = (const float*)d_in[6];
  const float* wt    = (const float*)d_in[7];
  const float* ttm_g = (const float*)d_in[8];
  const float* ttm_b = (const float*)d_in[9];
  const float* thp_w = (const float*)d_in[10];
  const float* thp_b = (const float*)d_in[11];
  const float* thp_g = (const float*)d_in[12];
  const float* thp_e = (const float*)d_in[13];
  const float* w1    = (const float*)d_in[14];
  const float* b1    = (const float*)d_in[15];
  const float* tn_g  = (const float*)d_in[16];
  const float* tn_e  = (const float*)d_in[17];
  const float* w2    = (const float*)d_in[18];
  const float* b2    = (const float*)d_in[19];

  char* ws = (char*)d_ws;
  size_t off = 0;
  auto alloc = [&](size_t bytes) {
    void* p = ws + off;
    off = (off + bytes + 255) & ~(size_t)255;
    return p;
  };

  __hip_bfloat16* xb    = (__hip_bfloat16*)alloc((size_t)BS_ * H_ * 2);
  __hip_bfloat16* wcat  = (__hip_bfloat16*)alloc((size_t)H6_ * H_ * 2);
  __hip_bfloat16* wob   = (__hip_bfloat16*)alloc((size_t)H_ * H_ * 2);
  __hip_bfloat16* w1b   = (__hip_bfloat16*)alloc((size_t)H_ * 2 * H_ * 2);
  __hip_bfloat16* qkv2  = (__hip_bfloat16*)alloc((size_t)BS_ * H6_ * 2);
  __hip_bfloat16* vt2   = (__hip_bfloat16*)alloc((size_t)128 * DH_ * S_ * 2);
  __hip_bfloat16* mctxb = (__hip_bfloat16*)alloc((size_t)BS_ * H_ * 2);
  __hip_bfloat16* tob   = (__hip_bfloat16*)alloc((size_t)BS_ * H_ * 2);
  float* weff  = (float*)alloc((size_t)NH_ * H_ * 4);
  float* T0    = (float*)alloc((size_t)BS_ * NH_ * 4);
  float* xw1a  = (float*)alloc((size_t)BS_ * H_ * 4);
  float* tbw   = (float*)alloc((size_t)BS_ * H_ * 4);
  float* temps = (float*)alloc((size_t)3 * BS_ * 4);
  float* twn   = (float*)alloc((size_t)BS_ * 4);
  float* rsum  = (float*)alloc((size_t)H_ * 4);

  const float scale = 0.125f;
  dim3 blk(256);

  // ---- prep: weff zero (64KB) + casts + weff + rowsum (1 memset + 1 dispatch) ----
  hipMemsetAsync(weff, 0, (size_t)NH_ * H_ * 4, stream);
  PrepArgs pa;
  pa.s[0] = {x, (unsigned short*)xb, BS_ * H_};
  pa.s[1] = {w_in, (unsigned short*)wcat, 3 * H_ * H_};
  pa.s[2] = {wq, (unsigned short*)wcat + (size_t)3 * H_ * H_, H_ * H_};
  pa.s[3] = {wk, (unsigned short*)wcat + (size_t)4 * H_ * H_, H_ * H_};
  pa.s[4] = {wv, (unsigned short*)wcat + (size_t)5 * H_ * H_, H_ * H_};
  pa.s[5] = {wo, (unsigned short*)wob, H_ * H_};
  pa.s[6] = {w1, (unsigned short*)w1b, 2 * H_ * H_};
  pa.wt = wt; pa.wout = w_out; pa.weff = weff; pa.w1 = w1; pa.rsum = rsum;
  prep_k<<<dim3((BS_ * H_ + 1023) / 1024, 9), blk, 0, stream>>>(pa);

  // ---- merged qkv GEMM (writes Q/K rows + V transposed) ----
  gemm_qkv_k<<<dim3(H6_ / 128, BS_ / 128), blk, 0, stream>>>(xb, wcat, qkv2, vt2);

  // ---- ttm attention -> mctx; wt-projection -> T0; thp -> T_base ----
  flash_k<true><<<dim3(64, 8), blk, 0, stream>>>(qkv2, vt2, (const float*)nullptr, mctxb,
                                                 scale, H6_);
  wtproj_k<<<BS_ / 16, blk, 0, stream>>>(mctxb, weff, ttm_g, ttm_b, T0);
  thp_k<<<BS_, blk, 0, stream>>>(T0, thp_w, thp_b, thp_g, thp_e, tob, temps);

  // ---- temp_net: dual-A GEMM (K=2048) + fused iterations + stats ----
  gemm_bt<4, 2, 2, 2, true><<<dim3(H_ / 64, BS_ / 128), blk, 0, stream>>>(
      xb, w1b, tbw, 2 * H_, H_, 2 * H_, H_, tob, xw1a, H_);
  hlnrd2_k<<<BS_, blk, 0, stream>>>(xw1a, tbw, rsum, b1, tn_g, tn_e, w2, b2,
                                    temps + BS_, temps + 2 * BS_);
  stats_k<<<1, blk, 0, stream>>>(temps, temps + BS_, temps + 2 * BS_, twn,
                                 (float*)d_out + (size_t)BS_ * H_);

  // ---- main attention + out-proj ----
  flash_k<false><<<dim3(64, 8), blk, 0, stream>>>(qkv2 + 3 * H_,
                                                  vt2 + (size_t)64 * DH_ * S_, twn, mctxb,
                                                  scale, H6_);
  gemm_bt<4, 2, 2, 2, false><<<dim3(H_ / 64, BS_ / 128), blk, 0, stream>>>(
      mctxb, wob, (float*)d_out, H_, H_, H_, H_, nullptr, nullptr, 0);
}

// Round 9
// 400.518 us; speedup vs baseline: 1.3104x; 1.0034x over previous
//
#include <hip/hip_runtime.h>
#include <hip/hip_bf16.h>

#define DEV __device__ __forceinline__

typedef short bf16x8 __attribute__((ext_vector_type(8)));
typedef short bf16x4 __attribute__((ext_vector_type(4)));
typedef float f32x4 __attribute__((ext_vector_type(4)));

static constexpr int B_  = 4;
static constexpr int S_  = 1024;
static constexpr int H_  = 1024;
static constexpr int NH_ = 16;
static constexpr int DH_ = 64;
static constexpr int BS_ = B_ * S_;   // 4096
static constexpr int H6_ = 6 * H_;    // 6144

// ---------------- async global->LDS (16B per lane) ----------------
DEV void gld16(const void* g, void* l) {
  __builtin_amdgcn_global_load_lds(
      (__attribute__((address_space(1))) void*)(unsigned long long)g,
      (__attribute__((address_space(3))) void*)(unsigned)(unsigned long long)l,
      16, 0, 0);
}

// 16x16x16 bf16 MFMA (A-frag layout matches C-layout of transposed scores)
DEV f32x4 pv_mfma(bf16x4 a, bf16x4 b, f32x4 c) {
#if __has_builtin(__builtin_amdgcn_mfma_f32_16x16x16bf16_1k)
  return __builtin_amdgcn_mfma_f32_16x16x16bf16_1k(a, b, c, 0, 0, 0);
#else
  asm volatile("v_mfma_f32_16x16x16_bf16 %0, %1, %2, %0" : "+v"(c) : "v"(a), "v"(b));
  return c;
#endif
}

// ---------------- reductions (blockDim == 256) ----------------
DEV float wred_sum(float v) {
#pragma unroll
  for (int o = 32; o; o >>= 1) v += __shfl_xor(v, o);
  return v;
}
DEV float bred_sum(float v, float* sh) {
  v = wred_sum(v);
  const int tid = threadIdx.x;
  if ((tid & 63) == 0) sh[tid >> 6] = v;
  __syncthreads();
  v = sh[0] + sh[1] + sh[2] + sh[3];
  __syncthreads();
  return v;
}
DEV float geluf(float x) { return 0.5f * x * (1.f + erff(x * 0.70710678118654752f)); }

// ---------------- prep: casts + weff + rowsum in ONE dispatch ----------------
struct CastSeg { const float* src; unsigned short* dst; int n; };
struct PrepArgs {
  CastSeg s[7];
  const float* wt; const float* wout; float* weff;
  const float* w1; float* rsum;
};
__global__ __launch_bounds__(256) void prep_k(PrepArgs a) {
  const int y = blockIdx.y, tid = threadIdx.x;
  if (y < 7) {
    const CastSeg g = a.s[y];
    int i = (blockIdx.x * 256 + tid) * 4;
    if (i >= g.n) return;
    float4 v = *(const float4*)(g.src + i);
    __hip_bfloat16 o0 = __float2bfloat16(v.x), o1 = __float2bfloat16(v.y);
    __hip_bfloat16 o2 = __float2bfloat16(v.z), o3 = __float2bfloat16(v.w);
    ushort4 o;
    o.x = *(unsigned short*)&o0; o.y = *(unsigned short*)&o1;
    o.z = *(unsigned short*)&o2; o.w = *(unsigned short*)&o3;
    *(ushort4*)(g.dst + i) = o;
  } else if (y == 7) {
    // weff[n,h] += sum over o-chunk of wt[n,o]*wout[o,h]; 256 blocks, atomic combine
    if (blockIdx.x >= 256) return;
    const int h = (blockIdx.x & 15) * 64 + (tid & 63), ng = tid >> 6;
    const int o0 = (blockIdx.x >> 4) * 64;
    float acc[4] = {0.f, 0.f, 0.f, 0.f};
#pragma unroll 8
    for (int o = o0; o < o0 + 64; o++) {
      float wv = a.wout[(size_t)o * H_ + h];
#pragma unroll
      for (int i = 0; i < 4; i++) acc[i] += a.wt[(size_t)(ng * 4 + i) * H_ + o] * wv;
    }
#pragma unroll
    for (int i = 0; i < 4; i++) atomicAdd(&a.weff[(size_t)(ng * 4 + i) * H_ + h], acc[i]);
  } else {
    // rowsum of W1b (fp32 exact)
    if (blockIdx.x >= 256) return;
    const int row = blockIdx.x * 4 + (tid >> 6), lane = tid & 63;
    float s = 0.f;
#pragma unroll
    for (int j = 0; j < 16; j++) s += a.w1[(size_t)row * 2048 + 1024 + lane + j * 64];
    s = wred_sum(s);
    if (lane == 0) a.rsum[row] = s;
  }
}

// ---------------- QKV GEMM (N=6144), dbuf prefetch, V-transposed epilogue ----------------
__global__ __launch_bounds__(256) void gemm_qkv_k(
    const __hip_bfloat16* __restrict__ Ap, const __hip_bfloat16* __restrict__ Wp,
    __hip_bfloat16* __restrict__ Cp, __hip_bfloat16* __restrict__ vt2) {
  constexpr int BK = 32;
  __shared__ __align__(16) short smem[16384];  // A dbuf @0/@4096, B dbuf @8192/@12288; sT aliases
  const int tid = threadIdx.x;
  const int wave = tid >> 6, lane = tid & 63;
  const int wm = wave >> 1, wn = wave & 1;
  const int lr = lane & 15, kq = lane >> 4;
  const int bx = blockIdx.x, by = blockIdx.y;
  const short* Ab = (const short*)Ap + (long long)by * 128 * H_;
  const short* Wb = (const short*)Wp + (long long)bx * 128 * H_;

  auto stage = [&](int k0, int buf) {
    short* sA = smem + buf * 4096;
    short* sB = smem + 8192 + buf * 4096;
#pragma unroll
    for (int r = 0; r < 2; r++) {
      int idx = r * 256 + tid;
      gld16(Ab + (long long)(idx >> 2) * H_ + k0 + (idx & 3) * 8, sA + (size_t)idx * 8);
    }
#pragma unroll
    for (int r = 0; r < 2; r++) {
      int idx = r * 256 + tid;
      gld16(Wb + (long long)(idx >> 2) * H_ + k0 + (idx & 3) * 8, sB + (size_t)idx * 8);
    }
  };

  f32x4 acc[4][4];
#pragma unroll
  for (int i = 0; i < 4; i++)
#pragma unroll
    for (int j = 0; j < 4; j++) acc[i][j] = f32x4{0.f, 0.f, 0.f, 0.f};

  stage(0, 0);
  __syncthreads();  // vmcnt(0) drain: buf0 ready

  for (int it = 0; it < H_ / BK; it++) {
    const int cur = it & 1;
    if (it < H_ / BK - 1) stage((it + 1) * BK, cur ^ 1);
    const short* sA = smem + cur * 4096;
    const short* sB = smem + 8192 + cur * 4096;
    bf16x8 af[4], bfr[4];
#pragma unroll
    for (int i = 0; i < 4; i++)
      af[i] = *(const bf16x8*)(sA + (wm * 64 + i * 16 + lr) * BK + kq * 8);
#pragma unroll
    for (int j = 0; j < 4; j++)
      bfr[j] = *(const bf16x8*)(sB + (wn * 64 + j * 16 + lr) * BK + kq * 8);
#pragma unroll
    for (int i = 0; i < 4; i++)
#pragma unroll
      for (int j = 0; j < 4; j++)
        acc[i][j] = __builtin_amdgcn_mfma_f32_16x16x32_bf16(af[i], bfr[j], acc[i][j], 0, 0, 0);
    __syncthreads();  // waves done with cur; prefetch into cur^1 drained
  }

  const bool isV = (bx >= 16 && bx < 24) || (bx >= 40);
  if (!isV) {
    const long long row0 = (long long)by * 128 + wm * 64 + kq * 4;
    const long long col0 = (long long)bx * 128 + wn * 64 + lr;
#pragma unroll
    for (int i = 0; i < 4; i++)
#pragma unroll
      for (int j = 0; j < 4; j++)
#pragma unroll
        for (int r = 0; r < 4; r++)
          Cp[(row0 + i * 16 + r) * H6_ + col0 + j * 16] = __float2bfloat16(acc[i][j][r]);
  } else {
    short* sT = smem;
    const int sel = bx >= 40;
    const int h0 = (bx - (sel ? 40 : 16)) * 2;
    const int b = by >> 3, s0 = (by & 7) * 128;
#pragma unroll
    for (int hh = 0; hh < 2; hh++) {
      __syncthreads();
      if (wn == hh) {
#pragma unroll
        for (int i = 0; i < 4; i++)
#pragma unroll
          for (int j = 0; j < 4; j++)
#pragma unroll
            for (int r = 0; r < 4; r++) {
              __hip_bfloat16 v = __float2bfloat16(acc[i][j][r]);
              sT[(j * 16 + lr) * 132 + wm * 64 + i * 16 + kq * 4 + r] = *(short*)&v;
            }
      }
      __syncthreads();
      const int bh2 = sel * 64 + b * 16 + h0 + hh;
      short* dst = (short*)vt2 + (size_t)bh2 * DH_ * S_ + s0;
#pragma unroll
      for (int c = 0; c < 8; c++) {
        int flat = c * 256 + tid;
        int d = flat >> 5, s4 = (flat & 31) * 4;
        *(short4*)(dst + (size_t)d * S_ + s4) = *(short4*)(sT + d * 132 + s4);
      }
    }
  }
}

// ---------------- generic MFMA GEMM (fp32 out), dbuf prefetch, MID dual-A ----------------
template <int MT, int NT, int WR, int WC, bool MID>
__global__ __launch_bounds__(256) void gemm_bt(
    const __hip_bfloat16* __restrict__ Ap, const __hip_bfloat16* __restrict__ Wp,
    float* __restrict__ Cp, int K, int lda, int ldw, int ldc,
    const __hip_bfloat16* __restrict__ Ap2, float* __restrict__ Cmid, int kmid) {
  constexpr int BM = WR * MT * 16;
  constexpr int BN = WC * NT * 16;
  constexpr int BK = 32;
  __shared__ __align__(16) short sAs[2][BM * BK];
  __shared__ __align__(16) short sBs[2][BN * BK];
  const int tid = threadIdx.x;
  const int wave = tid >> 6, lane = tid & 63;
  const int wm = wave / WC, wn = wave % WC;
  const int lr = lane & 15, kq = lane >> 4;
  const short* Ab = (const short*)Ap + (long long)blockIdx.y * BM * lda;
  const short* Ab2 = MID ? (const short*)Ap2 + (long long)blockIdx.y * BM * lda : nullptr;
  const short* Wb = (const short*)Wp + (long long)blockIdx.x * BN * ldw;
  const long long row0 = (long long)blockIdx.y * BM + wm * MT * 16 + kq * 4;
  const long long col0 = (long long)blockIdx.x * BN + wn * NT * 16 + lr;

  auto stage = [&](int k0, int buf) {
    const short* Asrc;
    int ka;
    if (MID && k0 >= kmid) { Asrc = Ab2; ka = k0 - kmid; }
    else { Asrc = Ab; ka = k0; }
#pragma unroll
    for (int r = 0; r < BM / 64; r++) {
      int idx = r * 256 + tid;
      gld16(Asrc + (long long)(idx >> 2) * lda + ka + (idx & 3) * 8, &sAs[buf][(size_t)idx * 8]);
    }
#pragma unroll
    for (int r = 0; r < BN / 64; r++) {
      int idx = r * 256 + tid;
      gld16(Wb + (long long)(idx >> 2) * ldw + k0 + (idx & 3) * 8, &sBs[buf][(size_t)idx * 8]);
    }
  };

  f32x4 acc[MT][NT];
#pragma unroll
  for (int i = 0; i < MT; i++)
#pragma unroll
    for (int j = 0; j < NT; j++) acc[i][j] = f32x4{0.f, 0.f, 0.f, 0.f};

  stage(0, 0);
  __syncthreads();

  for (int k0 = 0; k0 < K; k0 += BK) {
    const int cur = (k0 / BK) & 1;
    if (k0 + BK < K) stage(k0 + BK, cur ^ 1);
    const short* sA = sAs[cur];
    const short* sB = sBs[cur];
    bf16x8 af[MT], bfr[NT];
#pragma unroll
    for (int i = 0; i < MT; i++)
      af[i] = *(const bf16x8*)(sA + (wm * MT * 16 + i * 16 + lr) * BK + kq * 8);
#pragma unroll
    for (int j = 0; j < NT; j++)
      bfr[j] = *(const bf16x8*)(sB + (wn * NT * 16 + j * 16 + lr) * BK + kq * 8);
#pragma unroll
    for (int i = 0; i < MT; i++)
#pragma unroll
      for (int j = 0; j < NT; j++)
        acc[i][j] = __builtin_amdgcn_mfma_f32_16x16x32_bf16(af[i], bfr[j], acc[i][j], 0, 0, 0);
    if constexpr (MID) {
      if (k0 + BK == kmid) {
#pragma unroll
        for (int i = 0; i < MT; i++)
#pragma unroll
          for (int j = 0; j < NT; j++)
#pragma unroll
            for (int r = 0; r < 4; r++)
              Cmid[(row0 + i * 16 + r) * ldc + col0 + j * 16] = acc[i][j][r];
      }
    }
    __syncthreads();
  }
#pragma unroll
  for (int i = 0; i < MT; i++)
#pragma unroll
    for (int j = 0; j < NT; j++)
#pragma unroll
      for (int r = 0; r < 4; r++)
        Cp[(row0 + i * 16 + r) * ldc + col0 + j * 16] = acc[i][j][r];
}

// ---------------- fused flash attention (no online max: scores bounded) ----------------
template <bool TTM>
__global__ __launch_bounds__(256) void flash_k(
    const __hip_bfloat16* __restrict__ qkvB,
    const __hip_bfloat16* __restrict__ vt,
    const float* __restrict__ twn,
    __hip_bfloat16* __restrict__ ctx,
    float scale, int ldq) {
  __shared__ __align__(16) short sK[2][128 * 64];
  __shared__ __align__(16) short sVT[2][64 * 128];
  const int bh = blockIdx.x, b = bh >> 4, h = bh & 15;
  const int qb = blockIdx.y;
  const int tid = threadIdx.x, lane = tid & 63, wid = tid >> 6;
  const int lr = lane & 15, quad = lane >> 4;
  const short* qg = (const short*)qkvB + ((size_t)(b * S_) + qb * 128) * ldq + h * 64;
  const short* kg = (const short*)qkvB + (size_t)b * S_ * ldq + H_ + h * 64;
  const short* vg = (const short*)vt + (size_t)bh * DH_ * S_;

  auto stage = [&](int kt, int buf) {
#pragma unroll
    for (int i = 0; i < 4; i++) {
      int idx = i * 256 + tid;
      int row = idx >> 3, cp = idx & 7;
      int c = cp ^ (row & 7);
      gld16(kg + (size_t)(kt * 128 + row) * ldq + c * 8, &sK[buf][(size_t)idx * 8]);
    }
#pragma unroll
    for (int i = 0; i < 4; i++) {
      int idx = i * 256 + tid;
      int row = idx >> 4, cp = idx & 15;
      int c = cp ^ (row & 15);
      gld16(vg + (size_t)row * S_ + kt * 128 + c * 8, &sVT[buf][(size_t)idx * 8]);
    }
  };

  bf16x8 bq[2][2];
#pragma unroll
  for (int nt = 0; nt < 2; nt++)
#pragma unroll
    for (int kk = 0; kk < 2; kk++)
      bq[nt][kk] =
          *(const bf16x8*)(qg + (size_t)(wid * 32 + nt * 16 + lr) * ldq + kk * 32 + quad * 8);

  float fs[2];
#pragma unroll
  for (int nt = 0; nt < 2; nt++) {
    int q = qb * 128 + wid * 32 + nt * 16 + lr;
    fs[nt] = TTM ? scale : scale * twn[b * S_ + q];
  }
  f32x4 O[2][4];
#pragma unroll
  for (int nt = 0; nt < 2; nt++)
#pragma unroll
    for (int dt = 0; dt < 4; dt++) O[nt][dt] = f32x4{0.f, 0.f, 0.f, 0.f};
  float lrow[2] = {0.f, 0.f};

  stage(0, 0);
  __syncthreads();

  for (int kt = 0; kt < 8; kt++) {
    const int cur = kt & 1;
    if (kt < 7) stage(kt + 1, cur ^ 1);
    const short* sKc = sK[cur];
    const short* sVc = sVT[cur];

    f32x4 Sa[8][2];
#pragma unroll
    for (int mt = 0; mt < 8; mt++)
#pragma unroll
      for (int nt = 0; nt < 2; nt++) Sa[mt][nt] = f32x4{0.f, 0.f, 0.f, 0.f};
#pragma unroll
    for (int mt = 0; mt < 8; mt++)
#pragma unroll
      for (int kk = 0; kk < 2; kk++) {
        int row = mt * 16 + lr;
        int cp = (kk * 4 + quad) ^ (lr & 7);
        bf16x8 ak = *(const bf16x8*)(sKc + row * 64 + cp * 8);
#pragma unroll
        for (int nt = 0; nt < 2; nt++)
          Sa[mt][nt] = __builtin_amdgcn_mfma_f32_16x16x32_bf16(ak, bq[nt][kk], Sa[mt][nt], 0, 0, 0);
      }

    bf16x4 Pf[8][2];
#pragma unroll
    for (int nt = 0; nt < 2; nt++) {
      float ls = 0.f;
#pragma unroll
      for (int mt = 0; mt < 8; mt++) {
        float p0 = __expf(Sa[mt][nt][0] * fs[nt]);
        float p1 = __expf(Sa[mt][nt][1] * fs[nt]);
        float p2 = __expf(Sa[mt][nt][2] * fs[nt]);
        float p3 = __expf(Sa[mt][nt][3] * fs[nt]);
        ls += (p0 + p1) + (p2 + p3);
        __hip_bfloat16 h0 = __float2bfloat16(p0), h1 = __float2bfloat16(p1);
        __hip_bfloat16 h2 = __float2bfloat16(p2), h3 = __float2bfloat16(p3);
        bf16x4 pk;
        pk[0] = *(short*)&h0; pk[1] = *(short*)&h1;
        pk[2] = *(short*)&h2; pk[3] = *(short*)&h3;
        Pf[mt][nt] = pk;
      }
      ls += __shfl_xor(ls, 16);
      ls += __shfl_xor(ls, 32);
      lrow[nt] += ls;
    }

#pragma unroll
    for (int mt = 0; mt < 8; mt++)
#pragma unroll
      for (int dt = 0; dt < 4; dt++) {
        int row = dt * 16 + lr;
        int cp = (2 * mt + (quad >> 1)) ^ lr;
        bf16x4 bv = *(const bf16x4*)(sVc + row * 128 + cp * 8 + (quad & 1) * 4);
#pragma unroll
        for (int nt = 0; nt < 2; nt++) O[nt][dt] = pv_mfma(Pf[mt][nt], bv, O[nt][dt]);
      }

    __syncthreads();
  }

#pragma unroll
  for (int nt = 0; nt < 2; nt++)
#pragma unroll
    for (int r = 0; r < 4; r++) {
      float li = __shfl(lrow[nt], quad * 4 + r);
      float inv = 1.f / li;
      int q = qb * 128 + wid * 32 + nt * 16 + quad * 4 + r;
      __hip_bfloat16* op = ctx + ((size_t)(b * S_) + q) * H_ + h * 64 + lr;
#pragma unroll
      for (int dt = 0; dt < 4; dt++)
        op[dt * 16] = __float2bfloat16(O[nt][dt][r] * inv);
    }
}

// ---------------- MFMA wt-projection + LN(16) + sigmoid -> T0 ----------------
__global__ __launch_bounds__(256) void wtproj_k(const __hip_bfloat16* __restrict__ mctx,
                                                const float* __restrict__ weff,
                                                const float* __restrict__ g,
                                                const float* __restrict__ be,
                                                float* __restrict__ T0) {
  __shared__ float sC[4][256];
  const int tid = threadIdx.x, lane = tid & 63, wid = tid >> 6;
  const int lr = lane & 15, quad = lane >> 4;
  const int bs0 = blockIdx.x * 16;
  const short* aG = (const short*)mctx + (size_t)(bs0 + lr) * H_ + wid * 256;
  const float* bG = weff + (size_t)lr * H_ + wid * 256;
  f32x4 acc = f32x4{0.f, 0.f, 0.f, 0.f};
#pragma unroll
  for (int it = 0; it < 8; it++) {
    bf16x8 a = *(const bf16x8*)(aG + it * 32 + quad * 8);
    float4 b0 = *(const float4*)(bG + it * 32 + quad * 8);
    float4 b1 = *(const float4*)(bG + it * 32 + quad * 8 + 4);
    bf16x8 bb;
#pragma unroll
    for (int j = 0; j < 4; j++) {
      __hip_bfloat16 c0 = __float2bfloat16((&b0.x)[j]);
      __hip_bfloat16 c1 = __float2bfloat16((&b1.x)[j]);
      bb[j] = *(short*)&c0;
      bb[4 + j] = *(short*)&c1;
    }
    acc = __builtin_amdgcn_mfma_f32_16x16x32_bf16(a, bb, acc, 0, 0, 0);
  }
#pragma unroll
  for (int r = 0; r < 4; r++) sC[wid][(quad * 4 + r) * 16 + lr] = acc[r];
  __syncthreads();
  float tot = sC[0][tid] + sC[1][tid] + sC[2][tid] + sC[3][tid];
  const int n = tid & 15;
  float mean = tot;
#pragma unroll
  for (int o = 1; o < 16; o <<= 1) mean += __shfl_xor(mean, o);
  mean *= (1.f / 16.f);
  float d = tot - mean;
  float var = d * d;
#pragma unroll
  for (int o = 1; o < 16; o <<= 1) var += __shfl_xor(var, o);
  var *= (1.f / 16.f);
  float z = d * rsqrtf(var + 1e-5f) * g[n] + be[n];
  float t = 1.f / (1.f + expf(-z));
  T0[(size_t)blockIdx.x * 256 + tid] = 1.f + 0.1f * (t - 0.5f);
}

// ---------------- thp: sigmoid(gelu(LN(T0 @ thp_w^T + b))) ----------------
__global__ __launch_bounds__(256) void thp_k(const float* __restrict__ T0,
                                             const float* __restrict__ w,
                                             const float* __restrict__ bb,
                                             const float* __restrict__ g,
                                             const float* __restrict__ be,
                                             __hip_bfloat16* __restrict__ Tb,
                                             float* __restrict__ t0out) {
  __shared__ float sh[4];
  __shared__ float t0s[16];
  const int bs = blockIdx.x, tid = threadIdx.x;
  if (tid < 16) t0s[tid] = T0[(size_t)bs * 16 + tid];
  __syncthreads();
  float y[4];
#pragma unroll
  for (int i = 0; i < 4; i++) {
    int hh = tid + i * 256;
    const float* wr = w + (size_t)hh * 16;
    float a = bb[hh];
#pragma unroll
    for (int n = 0; n < 16; n++) a += t0s[n] * wr[n];
    y[i] = a;
  }
  float mean = bred_sum(y[0] + y[1] + y[2] + y[3], sh) * (1.f / 1024.f);
  float q = 0.f;
#pragma unroll
  for (int i = 0; i < 4; i++) { float d = y[i] - mean; q += d * d; }
  float var = bred_sum(q, sh) * (1.f / 1024.f);
  const float rs = rsqrtf(var + 1e-5f);
#pragma unroll
  for (int i = 0; i < 4; i++) {
    int hh = tid + i * 256;
    float z = (y[i] - mean) * rs * g[hh] + be[hh];
    float t = 1.f / (1.f + expf(-geluf(z)));
    Tb[(size_t)bs * H_ + hh] = __float2bfloat16(t);
    if (hh == 0) t0out[bs] = t;
  }
}

// ---------------- fused temp_net iterations 1+2 ----------------
__global__ __launch_bounds__(256) void hlnrd2_k(const float* __restrict__ xw1a,
                                                const float* __restrict__ tbwf,
                                                const float* __restrict__ rsum,
                                                const float* __restrict__ b1,
                                                const float* __restrict__ g,
                                                const float* __restrict__ be,
                                                const float* __restrict__ w2,
                                                const float* __restrict__ b2,
                                                float* __restrict__ t1out,
                                                float* __restrict__ t2out) {
  __shared__ float sh[4];
  const int bs = blockIdx.x, tid = threadIdx.x;
  float xa[4], bv[4], y[4];
#pragma unroll
  for (int i = 0; i < 4; i++) {
    int hh = tid + i * 256;
    xa[i] = xw1a[(size_t)bs * H_ + hh];
    bv[i] = b1[hh];
    y[i] = tbwf[(size_t)bs * H_ + hh] + bv[i];
  }
  float T1, T2;
#pragma unroll
  for (int iter = 0; iter < 2; iter++) {
    float mean = bred_sum(y[0] + y[1] + y[2] + y[3], sh) * (1.f / 1024.f);
    float q = 0.f;
#pragma unroll
    for (int i = 0; i < 4; i++) { float d = y[i] - mean; q += d * d; }
    float var = bred_sum(q, sh) * (1.f / 1024.f);
    const float rs = rsqrtf(var + 1e-5f);
    float s = 0.f;
#pragma unroll
    for (int i = 0; i < 4; i++) {
      int hh = tid + i * 256;
      float z = (y[i] - mean) * rs * g[hh] + be[hh];
      s += geluf(z) * w2[hh];
    }
    s = bred_sum(s, sh);
    float d = s + b2[0];
    float t = 1.f / (1.f + expf(-d));
    t = 1.f / (1.f + expf(-t));
    if (iter == 0) {
      T1 = t;
#pragma unroll
      for (int i = 0; i < 4; i++) {
        int hh = tid + i * 256;
        y[i] = xa[i] + T1 * rsum[hh] + bv[i];
      }
    } else {
      T2 = t;
    }
  }
  if (tid == 0) { t1out[bs] = T1; t2out[bs] = T2; }
}

// ---------------- global stats -> twn; scale_temps output ----------------
__global__ __launch_bounds__(256) void stats_k(const float* __restrict__ t0,
                                               const float* __restrict__ t1,
                                               const float* __restrict__ t2,
                                               float* __restrict__ twn,
                                               float* __restrict__ out2) {
  __shared__ float sh[4];
  const int tid = threadIdx.x;
  float s = 0.f;
  for (int i = tid; i < BS_; i += 256) s += (t0[i] + t1[i] + t2[i]) * (1.f / 3.f);
  const float mu = bred_sum(s, sh) * (1.f / (float)BS_);
  float q = 0.f;
  for (int i = tid; i < BS_; i += 256) {
    float tw = (t0[i] + t1[i] + t2[i]) * (1.f / 3.f);
    float d = tw - mu;
    q += d * d;
  }
  const float var = bred_sum(q, sh) * (1.f / (float)BS_);
  const float stdu = sqrtf(var);
  const float inv = 1.f / (stdu + 1.1920929e-07f);
  for (int i = tid; i < BS_; i += 256) {
    float tw = (t0[i] + t1[i] + t2[i]) * (1.f / 3.f);
    twn[i] = 1.f + (tw - mu) * inv;
  }
  for (int i = tid; i < 3 * BS_; i += 256) {
    int b = i / 3072, r = i - b * 3072;
    int j = r >> 10, ss = r & 1023;
    const float* tp = (j == 0) ? t0 : ((j == 1) ? t1 : t2);
    out2[i] = tp[b * S_ + ss];
  }
}

// =====================================================================
extern "C" void kernel_launch(void* const* d_in, const int* in_sizes, int n_in,
                              void* d_out, int out_size, void* d_ws, size_t ws_size,
                              hipStream_t stream) {
  (void)in_sizes; (void)n_in; (void)out_size; (void)ws_size;
  const float* x     = (const float*)d_in[0];
  const float* wq    = (const float*)d_in[1];
  const float* wk    = (const float*)d_in[2];
  const float* wv    = (const float*)d_in[3];
  const float* wo    = (const float*)d_in[4];
  const float* w_in  = (const float*)d_in[5];
  const float* w_out = (const float*)d_in[6];
  const float* wt    = (const float*)d_in[7];
  const float* ttm_g = (const float*)d_in[8];
  const float* ttm_b = (const float*)d_in[9];
  const float* thp_w = (const float*)d_in[10];
  const float* thp_b = (const float*)d_in[11];
  const float* thp_g = (const float*)d_in[12];
  const float* thp_e = (const float*)d_in[13];
  const float* w1    = (const float*)d_in[14];
  const float* b1    = (const float*)d_in[15];
  const float* tn_g  = (const float*)d_in[16];
  const float* tn_e  = (const float*)d_in[17];
  const float* w2    = (const float*)d_in[18];
  const float* b2    = (const float*)d_in[19];

  char* ws = (char*)d_ws;
  size_t off = 0;
  auto alloc = [&](size_t bytes) {
    void* p = ws + off;
    off = (off + bytes + 255) & ~(size_t)255;
    return p;
  };

  __hip_bfloat16* xb    = (__hip_bfloat16*)alloc((size_t)BS_ * H_ * 2);
  __hip_bfloat16* wcat  = (__hip_bfloat16*)alloc((size_t)H6_ * H_ * 2);
  __hip_bfloat16* wob   = (__hip_bfloat16*)alloc((size_t)H_ * H_ * 2);
  __hip_bfloat16* w1b   = (__hip_bfloat16*)alloc((size_t)H_ * 2 * H_ * 2);
  __hip_bfloat16* qkv2  = (__hip_bfloat16*)alloc((size_t)BS_ * H6_ * 2);
  __hip_bfloat16* vt2   = (__hip_bfloat16*)alloc((size_t)128 * DH_ * S_ * 2);
  __hip_bfloat16* mctxb = (__hip_bfloat16*)alloc((size_t)BS_ * H_ * 2);
  __hip_bfloat16* tob   = (__hip_bfloat16*)alloc((size_t)BS_ * H_ * 2);
  float* weff  = (float*)alloc((size_t)NH_ * H_ * 4);
  float* T0    = (float*)alloc((size_t)BS_ * NH_ * 4);
  float* xw1a  = (float*)alloc((size_t)BS_ * H_ * 4);
  float* tbw   = (float*)alloc((size_t)BS_ * H_ * 4);
  float* temps = (float*)alloc((size_t)3 * BS_ * 4);
  float* twn   = (float*)alloc((size_t)BS_ * 4);
  float* rsum  = (float*)alloc((size_t)H_ * 4);

  const float scale = 0.125f;
  dim3 blk(256);

  // ---- prep: weff zero + casts + weff + rowsum ----
  (void)hipMemsetAsync(weff, 0, (size_t)NH_ * H_ * 4, stream);
  PrepArgs pa;
  pa.s[0] = {x, (unsigned short*)xb, BS_ * H_};
  pa.s[1] = {w_in, (unsigned short*)wcat, 3 * H_ * H_};
  pa.s[2] = {wq, (unsigned short*)wcat + (size_t)3 * H_ * H_, H_ * H_};
  pa.s[3] = {wk, (unsigned short*)wcat + (size_t)4 * H_ * H_, H_ * H_};
  pa.s[4] = {wv, (unsigned short*)wcat + (size_t)5 * H_ * H_, H_ * H_};
  pa.s[5] = {wo, (unsigned short*)wob, H_ * H_};
  pa.s[6] = {w1, (unsigned short*)w1b, 2 * H_ * H_};
  pa.wt = wt; pa.wout = w_out; pa.weff = weff; pa.w1 = w1; pa.rsum = rsum;
  prep_k<<<dim3((BS_ * H_ + 1023) / 1024, 9), blk, 0, stream>>>(pa);

  // ---- merged qkv GEMM (writes Q/K rows + V transposed) ----
  gemm_qkv_k<<<dim3(H6_ / 128, BS_ / 128), blk, 0, stream>>>(xb, wcat, qkv2, vt2);

  // ---- ttm attention -> mctx; wt-projection -> T0; thp -> T_base ----
  flash_k<true><<<dim3(64, 8), blk, 0, stream>>>(qkv2, vt2, (const float*)nullptr, mctxb,
                                                 scale, H6_);
  wtproj_k<<<BS_ / 16, blk, 0, stream>>>(mctxb, weff, ttm_g, ttm_b, T0);
  thp_k<<<BS_, blk, 0, stream>>>(T0, thp_w, thp_b, thp_g, thp_e, tob, temps);

  // ---- temp_net: dual-A GEMM (K=2048) + fused iterations + stats ----
  gemm_bt<4, 2, 2, 2, true><<<dim3(H_ / 64, BS_ / 128), blk, 0, stream>>>(
      xb, w1b, tbw, 2 * H_, H_, 2 * H_, H_, tob, xw1a, H_);
  hlnrd2_k<<<BS_, blk, 0, stream>>>(xw1a, tbw, rsum, b1, tn_g, tn_e, w2, b2,
                                    temps + BS_, temps + 2 * BS_);
  stats_k<<<1, blk, 0, stream>>>(temps, temps + BS_, temps + 2 * BS_, twn,
                                 (float*)d_out + (size_t)BS_ * H_);

  // ---- main attention + out-proj ----
  flash_k<false><<<dim3(64, 8), blk, 0, stream>>>(qkv2 + 3 * H_,
                                                  vt2 + (size_t)64 * DH_ * S_, twn, mctxb,
                                                  scale, H6_);
  gemm_bt<4, 2, 2, 2, false><<<dim3(H_ / 64, BS_ / 128), blk, 0, stream>>>(
      mctxb, wob, (float*)d_out, H_, H_, H_, H_, nullptr, nullptr, 0);
}